// Round 1
// baseline (957.958 us; speedup 1.0000x reference)
//
#include <hip/hip_runtime.h>
#include <hip/hip_bf16.h>

// Problem: N=4, Cin=512, Cout=C=256, D=256, H=128, W=128, S=H*W=16384
// Pipeline:
//   k = relu(conv1(feat)*bn_scale + bn_shift)        [N,256,S]   (GEMM K=512)
//   energy[n,d,c] = sum_s q[n,d,s]*k[n,c,s]          [N,256,256] (GEMM K=16384, split-K)
//   att = softmax(-energy) over c                    (max-shift cancels)
//   M2[n,o,d] = sum_c w2[o,c]*att[n,d,c]             (tiny fused GEMM: W2 @ att^T)
//   out[n,o,s] = sum_d M2[n,o,d]*q[n,d,s] + b2[o]    (GEMM K=256)
// All fp32 this round (no fp32 MFMA on CDNA4 -> VALU GEMMs).

#define S_DIM 16384
#define C_DIM 256
#define CIN 512
#define NB 4

// ---------------- fold BN into conv1 weights ----------------
__global__ void fold_kernel(const float* __restrict__ w1, const float* __restrict__ gamma,
                            const float* __restrict__ beta, const float* __restrict__ mean,
                            const float* __restrict__ var, float* __restrict__ w1s,
                            float* __restrict__ b1) {
    int o = blockIdx.x;  // 256
    float sc = gamma[o] * rsqrtf(var[o] + 1e-5f);
    for (int i = threadIdx.x; i < CIN; i += blockDim.x)
        w1s[o * CIN + i] = w1[o * CIN + i] * sc;
    if (threadIdx.x == 0) b1[o] = beta[o] - mean[o] * sc;
}

__global__ void zero_kernel(float* __restrict__ p, int n) {
    int i = blockIdx.x * blockDim.x + threadIdx.x;
    if (i < n) p[i] = 0.0f;
}

// ---------------- generic fp32 GEMM: C[m,s] = act(sum_k A[m,k]*B[k,s] + bias[m]) ----------
// A row-major [M x K] (stride sA per batch), B row-major [K x S] (stride sB), C [M x S].
// Block tile 128x128, 256 threads, 8x8 micro-tile, K-step 16.
__global__ __launch_bounds__(256) void gemm_kernel(
    const float* __restrict__ A, long sA,
    const float* __restrict__ B, long sB,
    const float* __restrict__ bias,
    float* __restrict__ C, long sC,
    int K, int relu) {
    int n = blockIdx.z;
    int m0 = blockIdx.y * 128;
    int s0 = blockIdx.x * 128;
    const float* Ab = A + (size_t)n * sA;
    const float* Bb = B + (size_t)n * sB;
    float* Cb = C + (size_t)n * sC;

    __shared__ float As[16][132];  // As[kk][m]  (A tile transposed)
    __shared__ float Bs[16][132];  // Bs[kk][s]

    int tid = threadIdx.x;
    int tx = tid & 15;   // s-group
    int ty = tid >> 4;   // m-group
    float acc[8][8] = {};

    for (int kb = 0; kb < K; kb += 16) {
        // stage A tile (2048 scalars, transposed into LDS)
#pragma unroll
        for (int p = 0; p < 8; ++p) {
            int e = tid + p * 256;
            int kk = e & 15;
            int m = e >> 4;
            As[kk][m] = Ab[(size_t)(m0 + m) * K + kb + kk];
        }
        // stage B tile (512 float4, coalesced)
#pragma unroll
        for (int p = 0; p < 2; ++p) {
            int e = tid + p * 256;
            int kk = e >> 5;
            int x4 = (e & 31) * 4;
            *(float4*)&Bs[kk][x4] = *(const float4*)&Bb[(size_t)(kb + kk) * S_DIM + s0 + x4];
        }
        __syncthreads();
#pragma unroll
        for (int kk = 0; kk < 16; ++kk) {
            float a[8], b[8];
            *(float4*)&a[0] = *(const float4*)&As[kk][ty * 8];
            *(float4*)&a[4] = *(const float4*)&As[kk][ty * 8 + 4];
            *(float4*)&b[0] = *(const float4*)&Bs[kk][tx * 8];
            *(float4*)&b[4] = *(const float4*)&Bs[kk][tx * 8 + 4];
#pragma unroll
            for (int i = 0; i < 8; ++i)
#pragma unroll
                for (int j = 0; j < 8; ++j) acc[i][j] += a[i] * b[j];
        }
        __syncthreads();
    }
    // epilogue
#pragma unroll
    for (int i = 0; i < 8; ++i) {
        int m = m0 + ty * 8 + i;
        float bi = bias[m];
        float o[8];
#pragma unroll
        for (int j = 0; j < 8; ++j) {
            float v = acc[i][j] + bi;
            o[j] = relu ? fmaxf(v, 0.0f) : v;
        }
        float* dst = &Cb[(size_t)m * S_DIM + s0 + tx * 8];
        *(float4*)&dst[0] = *(float4*)&o[0];
        *(float4*)&dst[4] = *(float4*)&o[4];
    }
}

// ---------------- energy: E[n,d,c] += sum_{s in chunk} q[n,d,s]*k[n,c,s] ----------------
// Block: 128d x 128c tile, s-chunk = 512 (32 splits), atomic fp32 accumulate.
__global__ __launch_bounds__(256) void energy_kernel(
    const float* __restrict__ q,   // [N][256][S]
    const float* __restrict__ kv,  // [N][256][S]
    float* __restrict__ E) {       // [N][256][256] (pre-zeroed)
    const int CHUNK = 512;
    int split = blockIdx.x;        // 0..31
    int dt = blockIdx.y >> 1;
    int ct = blockIdx.y & 1;
    int n = blockIdx.z;
    int d0 = dt * 128, c0 = ct * 128;
    const float* qb = q + ((size_t)n * C_DIM + d0) * S_DIM;
    const float* kb = kv + ((size_t)n * C_DIM + c0) * S_DIM;
    int sb0 = split * CHUNK;

    __shared__ float Qs[32][132];  // Qs[ss][d]
    __shared__ float Ks[32][132];  // Ks[ss][c]
    int tid = threadIdx.x;
    int tx = tid & 15;   // c-group
    int ty = tid >> 4;   // d-group
    float acc[8][8] = {};

    for (int sb = sb0; sb < sb0 + CHUNK; sb += 32) {
#pragma unroll
        for (int p = 0; p < 4; ++p) {
            int f4 = tid + p * 256;  // 0..1023
            int r = f4 >> 3;         // row 0..127
            int s4 = (f4 & 7) * 4;
            float4 v = *(const float4*)&qb[(size_t)r * S_DIM + sb + s4];
            Qs[s4 + 0][r] = v.x; Qs[s4 + 1][r] = v.y; Qs[s4 + 2][r] = v.z; Qs[s4 + 3][r] = v.w;
            float4 w = *(const float4*)&kb[(size_t)r * S_DIM + sb + s4];
            Ks[s4 + 0][r] = w.x; Ks[s4 + 1][r] = w.y; Ks[s4 + 2][r] = w.z; Ks[s4 + 3][r] = w.w;
        }
        __syncthreads();
#pragma unroll
        for (int ss = 0; ss < 32; ++ss) {
            float a[8], b[8];
            *(float4*)&a[0] = *(const float4*)&Qs[ss][ty * 8];
            *(float4*)&a[4] = *(const float4*)&Qs[ss][ty * 8 + 4];
            *(float4*)&b[0] = *(const float4*)&Ks[ss][tx * 8];
            *(float4*)&b[4] = *(const float4*)&Ks[ss][tx * 8 + 4];
#pragma unroll
            for (int i = 0; i < 8; ++i)
#pragma unroll
                for (int j = 0; j < 8; ++j) acc[i][j] += a[i] * b[j];
        }
        __syncthreads();
    }
#pragma unroll
    for (int i = 0; i < 8; ++i) {
        int d = d0 + ty * 8 + i;
#pragma unroll
        for (int j = 0; j < 8; ++j) {
            int c = c0 + tx * 8 + j;
            atomicAdd(&E[((size_t)n * C_DIM + d) * C_DIM + c], acc[i][j]);
        }
    }
}

// ---------------- softmax(-E) over c, one block per (n,d) row ----------------
__global__ __launch_bounds__(256) void softmax_kernel(const float* __restrict__ E,
                                                      float* __restrict__ att) {
    int row = blockIdx.x;  // n*256+d
    int c = threadIdx.x;
    float v = E[(size_t)row * C_DIM + c];
    // row min (softmax(-E) peaks at min E)
    float m = v;
#pragma unroll
    for (int o = 32; o > 0; o >>= 1) m = fminf(m, __shfl_xor(m, o, 64));
    __shared__ float red[4];
    __shared__ float red2[4];
    int lane = c & 63, wid = c >> 6;
    if (lane == 0) red[wid] = m;
    __syncthreads();
    m = fminf(fminf(red[0], red[1]), fminf(red[2], red[3]));
    float e = expf(m - v);  // <= 1
    float s = e;
#pragma unroll
    for (int o = 32; o > 0; o >>= 1) s += __shfl_xor(s, o, 64);
    if (lane == 0) red2[wid] = s;
    __syncthreads();
    s = red2[0] + red2[1] + red2[2] + red2[3];
    att[(size_t)row * C_DIM + c] = e / s;
}

// ---------------- M2[n,o,d] = sum_c w2[o,c]*att[n,d,c]  (tiny) ----------------
__global__ __launch_bounds__(256) void m2_kernel(const float* __restrict__ w2,
                                                 const float* __restrict__ att,
                                                 float* __restrict__ M2) {
    int t = blockIdx.x * 256 + threadIdx.x;  // 262144 threads
    int d = t & 255;
    int o = (t >> 8) & 255;
    int n = t >> 16;
    const float4* wr = (const float4*)(w2 + (size_t)o * C_DIM);          // shared in block
    const float4* ar = (const float4*)(att + ((size_t)n * C_DIM + d) * C_DIM);
    float s = 0.0f;
#pragma unroll 4
    for (int c4 = 0; c4 < 64; ++c4) {
        float4 w = wr[c4];
        float4 a = ar[c4];
        s += w.x * a.x + w.y * a.y + w.z * a.z + w.w * a.w;
    }
    M2[((size_t)n * C_DIM + o) * C_DIM + d] = s;
}

extern "C" void kernel_launch(void* const* d_in, const int* in_sizes, int n_in,
                              void* d_out, int out_size, void* d_ws, size_t ws_size,
                              hipStream_t stream) {
    const float* feat   = (const float*)d_in[0];  // [4,512,16384]
    const float* coarse = (const float*)d_in[1];  // [4,256,16384]
    const float* w1     = (const float*)d_in[2];  // [256,512]
    const float* gamma  = (const float*)d_in[3];
    const float* beta   = (const float*)d_in[4];
    const float* mean   = (const float*)d_in[5];
    const float* var    = (const float*)d_in[6];
    const float* w2     = (const float*)d_in[7];  // [256,256]
    const float* b2     = (const float*)d_in[8];
    float* out = (float*)d_out;
    float* ws = (float*)d_ws;

    // ws layout (floats): needs ~70.8 MB
    float* kbuf = ws;                   // 4*256*16384 = 16777216
    float* E    = ws + 16777216;        // 262144
    float* att  = ws + 17039360;        // 262144
    float* M2   = ws + 17301504;        // 262144
    float* w1s  = ws + 17563648;        // 131072
    float* b1   = ws + 17694720;        // 256

    fold_kernel<<<256, 256, 0, stream>>>(w1, gamma, beta, mean, var, w1s, b1);
    zero_kernel<<<1024, 256, 0, stream>>>(E, NB * C_DIM * C_DIM);

    // conv1 + BN + relu -> kbuf : A=w1s(256x512, shared), B=feat, relu
    gemm_kernel<<<dim3(128, 2, NB), 256, 0, stream>>>(
        w1s, 0, feat, (long)CIN * S_DIM, b1, kbuf, (long)C_DIM * S_DIM, CIN, 1);

    // energy (split-K=32, atomics)
    energy_kernel<<<dim3(32, 4, NB), 256, 0, stream>>>(coarse, kbuf, E);

    softmax_kernel<<<NB * C_DIM, 256, 0, stream>>>(E, att);
    m2_kernel<<<1024, 256, 0, stream>>>(w2, att, M2);

    // out = M2 @ q + b2 : A=M2(per-n 256x256), B=coarse
    gemm_kernel<<<dim3(128, 2, NB), 256, 0, stream>>>(
        M2, (long)C_DIM * C_DIM, coarse, (long)C_DIM * S_DIM, b2, out, (long)C_DIM * S_DIM,
        C_DIM, 0);
}

// Round 2
// 496.789 us; speedup vs baseline: 1.9283x; 1.9283x over previous
//
#include <hip/hip_runtime.h>

// N=4, Cin=512, C=D=256, S=H*W=16384
// k = relu(BN(conv1(feat)))        : NT-MFMA GEMM, A=w1hi/lo [256x512], B=feat^T hi/lo (pre-transposed)
// E[d,c] = sum_s q[d,s] k[c,s]     : NT-MFMA GEMM (split-K=32, fp32 atomics), 3-pass hi/lo
// att = softmax(-E) over c          (max-shift cancels)
// M2[o,d] = sum_c w2[o,c] att[d,c] : tiny VALU kernel -> bf16
// out[o,s] = sum_d M2[o,d] q[d,s] + b2 : NT-MFMA single-pass, B=q^T hi
// Precision: hi/lo bf16 split (2x8 mantissa bits) keeps |dE| ~ 1e-3; bf16-only would give ~0.8.

#define S_DIM 16384
#define C_DIM 256
#define CIN 512

typedef unsigned short u16;
typedef __attribute__((ext_vector_type(8))) short bf16x8;
typedef __attribute__((ext_vector_type(4))) float f32x4;

__device__ __forceinline__ u16 f2bf(float x) {
    unsigned u = __float_as_uint(x);
    u += 0x7fff + ((u >> 16) & 1);
    return (u16)(u >> 16);
}
__device__ __forceinline__ float bf2f(u16 h) {
    return __uint_as_float(((unsigned)h) << 16);
}
__device__ __forceinline__ void gld16(const u16* g, u16* l) {
    __builtin_amdgcn_global_load_lds((const __attribute__((address_space(1))) void*)g,
                                     (__attribute__((address_space(3))) void*)l, 16, 0, 0);
}

// ---------------- fold BN into conv1 weights, split hi/lo ----------------
__global__ __launch_bounds__(128) void fold_split_w1(
    const float* __restrict__ w1, const float* __restrict__ gamma,
    const float* __restrict__ beta, const float* __restrict__ mean,
    const float* __restrict__ var, u16* __restrict__ whi, u16* __restrict__ wlo,
    float* __restrict__ b1) {
    int o = blockIdx.x;
    float sc = gamma[o] * rsqrtf(var[o] + 1e-5f);
    for (int i = threadIdx.x; i < CIN; i += 128) {
        float v = w1[o * CIN + i] * sc;
        u16 h = f2bf(v);
        whi[o * CIN + i] = h;
        wlo[o * CIN + i] = f2bf(v - bf2f(h));
    }
    if (threadIdx.x == 0) b1[o] = beta[o] - mean[o] * sc;
}

__global__ __launch_bounds__(256) void zero_kernel(float* __restrict__ p, int n) {
    int i = blockIdx.x * 256 + threadIdx.x;
    if (i < n) p[i] = 0.0f;
}

// ---------------- split coarse_x into qhi/qlo bf16 ----------------
__global__ __launch_bounds__(256) void split_q(const float* __restrict__ src,
                                               u16* __restrict__ qhi, u16* __restrict__ qlo) {
    size_t i = (size_t)blockIdx.x * 256 + threadIdx.x;
    for (size_t c = i; c < 4194304u; c += 1048576u) {
        float4 v = ((const float4*)src)[c];
        float vv[4] = {v.x, v.y, v.z, v.w};
        u16 h[4], l[4];
#pragma unroll
        for (int j = 0; j < 4; ++j) {
            h[j] = f2bf(vv[j]);
            l[j] = f2bf(vv[j] - bf2f(h[j]));
        }
        *(uint2*)&qhi[c * 4] = *(uint2*)h;
        *(uint2*)&qlo[c * 4] = *(uint2*)l;
    }
}

// ---------------- transpose+split feat: [512][16384] f32 -> [16384][512] bf16 hi/lo ------
__global__ __launch_bounds__(256) void transpose_feat(const float* __restrict__ src,
                                                      u16* __restrict__ dhi,
                                                      u16* __restrict__ dlo) {
    int s0 = blockIdx.x * 64;
    int i0 = blockIdx.y * 64;
    size_t sb = (size_t)blockIdx.z * 8388608;
    __shared__ u16 Th[64][65], Tl[64][65];
    int t = threadIdx.x;
#pragma unroll
    for (int p = 0; p < 4; ++p) {
        int idx = t + p * 256;
        int row = idx >> 4, c4 = (idx & 15) * 4;
        float4 v = *(const float4*)&src[sb + (size_t)(i0 + row) * S_DIM + s0 + c4];
        float vv[4] = {v.x, v.y, v.z, v.w};
#pragma unroll
        for (int j = 0; j < 4; ++j) {
            u16 h = f2bf(vv[j]);
            Th[c4 + j][row] = h;
            Tl[c4 + j][row] = f2bf(vv[j] - bf2f(h));
        }
    }
    __syncthreads();
#pragma unroll
    for (int p = 0; p < 2; ++p) {
        int idx = t + p * 256;
        int row = idx >> 3, c8 = (idx & 7) * 8;
        u16 hh[8], ll[8];
#pragma unroll
        for (int j = 0; j < 8; ++j) { hh[j] = Th[row][c8 + j]; ll[j] = Tl[row][c8 + j]; }
        *(uint4*)&dhi[sb + (size_t)(s0 + row) * CIN + i0 + c8] = *(uint4*)hh;
        *(uint4*)&dlo[sb + (size_t)(s0 + row) * CIN + i0 + c8] = *(uint4*)ll;
    }
}

// ---------------- transpose qhi: [256][16384] -> [16384][256] bf16 ----------------
__global__ __launch_bounds__(256) void transpose_q(const u16* __restrict__ src,
                                                   u16* __restrict__ dst) {
    int s0 = blockIdx.x * 64;
    int d0 = blockIdx.y * 64;
    size_t sb = (size_t)blockIdx.z * 4194304;
    __shared__ u16 T[64][65];
    int t = threadIdx.x;
#pragma unroll
    for (int p = 0; p < 2; ++p) {
        int idx = t + p * 256;
        int row = idx >> 3, c8 = (idx & 7) * 8;
        u16 v[8];
        *(uint4*)v = *(const uint4*)&src[sb + (size_t)(d0 + row) * S_DIM + s0 + c8];
#pragma unroll
        for (int j = 0; j < 8; ++j) T[c8 + j][row] = v[j];
    }
    __syncthreads();
#pragma unroll
    for (int p = 0; p < 2; ++p) {
        int idx = t + p * 256;
        int row = idx >> 3, c8 = (idx & 7) * 8;
        u16 v[8];
#pragma unroll
        for (int j = 0; j < 8; ++j) v[j] = T[row][c8 + j];
        *(uint4*)&dst[sb + (size_t)(s0 + row) * C_DIM + d0 + c8] = *(uint4*)v;
    }
}

// ---------------- NT MFMA GEMM: C[m,n] = sum_k A[m,k]*B[n,k] ----------------
// 128x128 tile, 256 thr (4 waves, 2x2 of 64x64), BK=32, 16x16x32 bf16 MFMA.
// SPLIT=3: A,B have hi+lo buffers, 3 passes (hh, hl, lh). SPLIT=1: hi only.
// EPI: 0 = split-K atomicAdd fp32 (energy)   [grid: (splits, 4 tiles, batch)]
//      1 = bias+relu+hi/lo bf16 store (conv1)[grid: (ntiles, mtiles, batch)]
//      2 = bias+fp32 store (final)
template <int SPLIT, int EPI>
__global__ __launch_bounds__(256) void gemm_nt(
    const u16* __restrict__ Ah, const u16* __restrict__ Al, long aStride,
    const u16* __restrict__ Bh, const u16* __restrict__ Bl, long bStride,
    int K, int kLen,
    const float* __restrict__ bias,
    float* __restrict__ outF, long oStrideF,
    u16* __restrict__ oHi, u16* __restrict__ oLo, long oStrideH,
    int ldOut) {
    __shared__ u16 AhS[4096];
    __shared__ u16 BhS[4096];
    __shared__ u16 AlS[SPLIT == 3 ? 4096 : 8];
    __shared__ u16 BlS[SPLIT == 3 ? 4096 : 8];

    int m0, n0, kBeg;
    if (EPI == 0) {
        kBeg = blockIdx.x * kLen;
        m0 = (blockIdx.y >> 1) * 128;
        n0 = (blockIdx.y & 1) * 128;
    } else {
        kBeg = 0;
        n0 = blockIdx.x * 128;
        m0 = blockIdx.y * 128;
    }
    int bz = blockIdx.z;
    int tid = threadIdx.x;
    int wave = tid >> 6, lane = tid & 63;

    // staging: chunk c -> row c>>2, k-16B-slot c&3; LDS dest = c*16B (wave-uniform + lane*16)
    int c0 = wave * 128 + lane;
    int c1 = c0 + 64;
    int r0 = c0 >> 2, k0 = (c0 & 3) * 8;
    int r1 = c1 >> 2, k1 = (c1 & 3) * 8;
    const u16* gAh0 = Ah + (size_t)bz * aStride + (size_t)(m0 + r0) * K + kBeg + k0;
    const u16* gAh1 = Ah + (size_t)bz * aStride + (size_t)(m0 + r1) * K + kBeg + k1;
    const u16* gBh0 = Bh + (size_t)bz * bStride + (size_t)(n0 + r0) * K + kBeg + k0;
    const u16* gBh1 = Bh + (size_t)bz * bStride + (size_t)(n0 + r1) * K + kBeg + k1;
    const u16 *gAl0 = nullptr, *gAl1 = nullptr, *gBl0 = nullptr, *gBl1 = nullptr;
    if (SPLIT == 3) {
        gAl0 = Al + (size_t)bz * aStride + (size_t)(m0 + r0) * K + kBeg + k0;
        gAl1 = Al + (size_t)bz * aStride + (size_t)(m0 + r1) * K + kBeg + k1;
        gBl0 = Bl + (size_t)bz * bStride + (size_t)(n0 + r0) * K + kBeg + k0;
        gBl1 = Bl + (size_t)bz * bStride + (size_t)(n0 + r1) * K + kBeg + k1;
    }

    int quad = lane >> 4, l15 = lane & 15;
    int wm = wave >> 1, wn = wave & 1;
    int aBase = (wm * 64 + l15) * 32 + quad * 8;
    int bBase = (wn * 64 + l15) * 32 + quad * 8;

    f32x4 zero = {0.f, 0.f, 0.f, 0.f};
    f32x4 acc[4][4];
#pragma unroll
    for (int i = 0; i < 4; ++i)
#pragma unroll
        for (int j = 0; j < 4; ++j) acc[i][j] = zero;

    for (int kb = 0; kb < kLen; kb += 32) {
        __syncthreads();
        gld16(gAh0, AhS + c0 * 8);
        gld16(gAh1, AhS + c1 * 8);
        gld16(gBh0, BhS + c0 * 8);
        gld16(gBh1, BhS + c1 * 8);
        gAh0 += 32; gAh1 += 32; gBh0 += 32; gBh1 += 32;
        if (SPLIT == 3) {
            gld16(gAl0, AlS + c0 * 8);
            gld16(gAl1, AlS + c1 * 8);
            gld16(gBl0, BlS + c0 * 8);
            gld16(gBl1, BlS + c1 * 8);
            gAl0 += 32; gAl1 += 32; gBl0 += 32; gBl1 += 32;
        }
        __syncthreads();

        bf16x8 a_h[4], b_h[4], a_l[4], b_l[4];
#pragma unroll
        for (int t = 0; t < 4; ++t) {
            a_h[t] = *(const bf16x8*)&AhS[aBase + t * 512];
            b_h[t] = *(const bf16x8*)&BhS[bBase + t * 512];
            if (SPLIT == 3) {
                a_l[t] = *(const bf16x8*)&AlS[aBase + t * 512];
                b_l[t] = *(const bf16x8*)&BlS[bBase + t * 512];
            }
        }
#pragma unroll
        for (int mt = 0; mt < 4; ++mt)
#pragma unroll
            for (int nt = 0; nt < 4; ++nt) {
                acc[mt][nt] = __builtin_amdgcn_mfma_f32_16x16x32_bf16(a_h[mt], b_h[nt], acc[mt][nt], 0, 0, 0);
                if (SPLIT == 3) {
                    acc[mt][nt] = __builtin_amdgcn_mfma_f32_16x16x32_bf16(a_h[mt], b_l[nt], acc[mt][nt], 0, 0, 0);
                    acc[mt][nt] = __builtin_amdgcn_mfma_f32_16x16x32_bf16(a_l[mt], b_h[nt], acc[mt][nt], 0, 0, 0);
                }
            }
    }

    // epilogue: D row = m0+wm*64+mt*16+quad*4+r, col = n0+wn*64+nt*16+l15
#pragma unroll
    for (int mt = 0; mt < 4; ++mt) {
#pragma unroll
        for (int r = 0; r < 4; ++r) {
            int row = m0 + wm * 64 + mt * 16 + quad * 4 + r;
            float bi = (EPI != 0) ? bias[row] : 0.f;
#pragma unroll
            for (int nt = 0; nt < 4; ++nt) {
                int cc = n0 + wn * 64 + nt * 16 + l15;
                float v = acc[mt][nt][r];
                if (EPI == 0) {
                    atomicAdd(&outF[(size_t)bz * oStrideF + (size_t)row * ldOut + cc], v);
                } else if (EPI == 1) {
                    v = fmaxf(v + bi, 0.f);
                    u16 h = f2bf(v);
                    size_t o = (size_t)bz * oStrideH + (size_t)row * ldOut + cc;
                    oHi[o] = h;
                    oLo[o] = f2bf(v - bf2f(h));
                } else {
                    outF[(size_t)bz * oStrideF + (size_t)row * ldOut + cc] = v + bi;
                }
            }
        }
    }
}

// ---------------- softmax(-E) over c ----------------
__global__ __launch_bounds__(256) void softmax_kernel(const float* __restrict__ E,
                                                      float* __restrict__ att) {
    int row = blockIdx.x;
    int c = threadIdx.x;
    float v = E[(size_t)row * C_DIM + c];
    float m = v;
#pragma unroll
    for (int o = 32; o > 0; o >>= 1) m = fminf(m, __shfl_xor(m, o, 64));
    __shared__ float red[4];
    __shared__ float red2[4];
    int lane = c & 63, wid = c >> 6;
    if (lane == 0) red[wid] = m;
    __syncthreads();
    m = fminf(fminf(red[0], red[1]), fminf(red[2], red[3]));
    float e = expf(m - v);
    float s = e;
#pragma unroll
    for (int o = 32; o > 0; o >>= 1) s += __shfl_xor(s, o, 64);
    if (lane == 0) red2[wid] = s;
    __syncthreads();
    s = red2[0] + red2[1] + red2[2] + red2[3];
    att[(size_t)row * C_DIM + c] = e / s;
}

// ---------------- M2h[n,o,d] = bf16( sum_c w2[o,c]*att[n,d,c] ) ----------------
__global__ __launch_bounds__(256) void m2h_kernel(const float* __restrict__ w2,
                                                  const float* __restrict__ att,
                                                  u16* __restrict__ M2h) {
    int t = blockIdx.x * 256 + threadIdx.x;
    int d = t & 255, o = (t >> 8) & 255, n = t >> 16;
    const float4* wr = (const float4*)(w2 + (size_t)o * C_DIM);
    const float4* ar = (const float4*)(att + ((size_t)n * C_DIM + d) * C_DIM);
    float s = 0.0f;
#pragma unroll 4
    for (int c4 = 0; c4 < 64; ++c4) {
        float4 w = wr[c4];
        float4 a = ar[c4];
        s += w.x * a.x + w.y * a.y + w.z * a.z + w.w * a.w;
    }
    M2h[((size_t)n * C_DIM + o) * C_DIM + d] = f2bf(s);
}

extern "C" void kernel_launch(void* const* d_in, const int* in_sizes, int n_in,
                              void* d_out, int out_size, void* d_ws, size_t ws_size,
                              hipStream_t stream) {
    const float* feat   = (const float*)d_in[0];
    const float* coarse = (const float*)d_in[1];
    const float* w1     = (const float*)d_in[2];
    const float* gamma  = (const float*)d_in[3];
    const float* beta   = (const float*)d_in[4];
    const float* mean   = (const float*)d_in[5];
    const float* var    = (const float*)d_in[6];
    const float* w2     = (const float*)d_in[7];
    const float* b2     = (const float*)d_in[8];
    float* out = (float*)d_out;

    char* base = (char*)d_ws;  // peak ~195 MB
    u16* qhi  = (u16*)(base);                    // [4][256][16384]
    u16* qlo  = (u16*)(base + 33554432);
    u16* khi  = (u16*)(base + 67108864);         // [4][256][16384]
    u16* klo  = (u16*)(base + 100663296);
    u16* fThi = (u16*)(base + 134217728);        // [2][16384][512] (pair-sized)
    u16* fTlo = (u16*)(base + 167772160);
    u16* qThi = (u16*)(base + 134217728);        // aliases fT (dead after conv phase)
    float* E   = (float*)(base + 201326592);     // [4][256][256]
    float* att = (float*)(base + 202375168);
    u16* M2h   = (u16*)(base + 203423744);       // [4][256][256]
    u16* w1hi  = (u16*)(base + 203948032);
    u16* w1lo  = (u16*)(base + 204210176);
    float* b1  = (float*)(base + 204472320);

    fold_split_w1<<<256, 128, 0, stream>>>(w1, gamma, beta, mean, var, w1hi, w1lo, b1);
    split_q<<<4096, 256, 0, stream>>>(coarse, qhi, qlo);
    zero_kernel<<<1024, 256, 0, stream>>>(E, 262144);

    for (int pair = 0; pair < 2; ++pair) {
        transpose_feat<<<dim3(256, 8, 2), 256, 0, stream>>>(feat + (size_t)pair * 16777216,
                                                            fThi, fTlo);
        gemm_nt<3, 1><<<dim3(128, 2, 2), 256, 0, stream>>>(
            w1hi, w1lo, 0, fThi, fTlo, 8388608, CIN, CIN, b1,
            nullptr, 0, khi + (size_t)pair * 8388608, klo + (size_t)pair * 8388608,
            4194304, S_DIM);
    }

    // energy: split-K 32, 512 blocks
    gemm_nt<3, 0><<<dim3(32, 4, 4), 256, 0, stream>>>(
        qhi, qlo, 4194304, khi, klo, 4194304, S_DIM, 512, nullptr,
        E, 65536, nullptr, nullptr, 0, C_DIM);

    softmax_kernel<<<1024, 256, 0, stream>>>(E, att);
    m2h_kernel<<<1024, 256, 0, stream>>>(w2, att, M2h);
    transpose_q<<<dim3(256, 4, 4), 256, 0, stream>>>(qhi, qThi);

    // out = M2 @ q^T + b2 (single-pass bf16)
    gemm_nt<1, 2><<<dim3(128, 2, 4), 256, 0, stream>>>(
        M2h, nullptr, 65536, qThi, nullptr, 4194304, C_DIM, C_DIM, b2,
        out, 4194304, nullptr, nullptr, 0, S_DIM);
}

// Round 3
// 496.176 us; speedup vs baseline: 1.9307x; 1.0012x over previous
//
#include <hip/hip_runtime.h>

// N=4, Cin=512, C=D=256, S=H*W=16384
// U0: fold w1 | split coarse->q hi/lo | transpose+split feat -> fT hi/lo   (one movement kernel)
// conv: k = relu(BN(conv1)) NT-MFMA 3-pass hi/lo, all 4 batches            (1024 blocks)
// energy: E_part[split] = q.k^T NT-MFMA 3-pass, plain partial stores       (512 blocks)
// U1: softmax(-sum(E_part)) | transpose qhi -> qT                          (one kernel)
// m2h: M2[o,d] = w2 @ att^T -> bf16
// final: out = M2 @ qT + b2, single-pass bf16 MFMA, fp32 out
// Precision: hi/lo bf16 split keeps |dE| ~1e-3 (plain bf16 -> ~0.8 -> softmax flips on near-ties).

#define S_DIM 16384
#define C_DIM 256
#define CIN 512

typedef unsigned short u16;
typedef __attribute__((ext_vector_type(8))) short bf16x8;
typedef __attribute__((ext_vector_type(4))) float f32x4;

__device__ __forceinline__ u16 f2bf(float x) {
    unsigned u = __float_as_uint(x);
    u += 0x7fff + ((u >> 16) & 1);
    return (u16)(u >> 16);
}
__device__ __forceinline__ float bf2f(u16 h) {
    return __uint_as_float(((unsigned)h) << 16);
}
__device__ __forceinline__ void gld16(const u16* g, u16* l) {
    __builtin_amdgcn_global_load_lds((const __attribute__((address_space(1))) void*)g,
                                     (__attribute__((address_space(3))) void*)l, 16, 0, 0);
}

// ================= U0: movement union =================
// blocks [0,8192)      : transpose+split feat [4][512][16384] f32 -> fT [4][16384][512] hi/lo
// blocks [8192,12288)  : split coarse -> qhi/qlo
// blocks [12288,12304) : fold BN into w1 -> w1hi/w1lo, b1
__global__ __launch_bounds__(256) void prep_kernel(
    const float* __restrict__ feat, const float* __restrict__ coarse,
    const float* __restrict__ w1, const float* __restrict__ gamma,
    const float* __restrict__ beta, const float* __restrict__ mean,
    const float* __restrict__ var,
    u16* __restrict__ fThi, u16* __restrict__ fTlo,
    u16* __restrict__ qhi, u16* __restrict__ qlo,
    u16* __restrict__ w1hi, u16* __restrict__ w1lo, float* __restrict__ b1) {
    __shared__ u16 Th[64][65], Tl[64][65];
    int b = blockIdx.x;
    int t = threadIdx.x;
    if (b < 8192) {
        // transpose_feat: s-tile (b&255), i-tile ((b>>8)&7), batch (b>>11)
        int s0 = (b & 255) * 64;
        int i0 = ((b >> 8) & 7) * 64;
        size_t sb = (size_t)(b >> 11) * 8388608;
#pragma unroll
        for (int p = 0; p < 4; ++p) {
            int idx = t + p * 256;
            int row = idx >> 4, c4 = (idx & 15) * 4;
            float4 v = *(const float4*)&feat[sb + (size_t)(i0 + row) * S_DIM + s0 + c4];
            float vv[4] = {v.x, v.y, v.z, v.w};
#pragma unroll
            for (int j = 0; j < 4; ++j) {
                u16 h = f2bf(vv[j]);
                Th[c4 + j][row] = h;
                Tl[c4 + j][row] = f2bf(vv[j] - bf2f(h));
            }
        }
        __syncthreads();
#pragma unroll
        for (int p = 0; p < 2; ++p) {
            int idx = t + p * 256;
            int row = idx >> 3, c8 = (idx & 7) * 8;
            u16 hh[8], ll[8];
#pragma unroll
            for (int j = 0; j < 8; ++j) { hh[j] = Th[row][c8 + j]; ll[j] = Tl[row][c8 + j]; }
            *(uint4*)&fThi[sb + (size_t)(s0 + row) * CIN + i0 + c8] = *(uint4*)hh;
            *(uint4*)&fTlo[sb + (size_t)(s0 + row) * CIN + i0 + c8] = *(uint4*)ll;
        }
    } else if (b < 12288) {
        size_t i = (size_t)(b - 8192) * 256 + t;
        for (size_t c = i; c < 4194304u; c += 1048576u) {
            float4 v = ((const float4*)coarse)[c];
            float vv[4] = {v.x, v.y, v.z, v.w};
            u16 h[4], l[4];
#pragma unroll
            for (int j = 0; j < 4; ++j) {
                h[j] = f2bf(vv[j]);
                l[j] = f2bf(vv[j] - bf2f(h[j]));
            }
            *(uint2*)&qhi[c * 4] = *(uint2*)h;
            *(uint2*)&qlo[c * 4] = *(uint2*)l;
        }
    } else {
        int o = (b - 12288) * 16 + (t >> 4);
        int lane16 = t & 15;
        float sc = gamma[o] * rsqrtf(var[o] + 1e-5f);
        for (int i = lane16; i < CIN; i += 16) {
            float v = w1[o * CIN + i] * sc;
            u16 h = f2bf(v);
            w1hi[o * CIN + i] = h;
            w1lo[o * CIN + i] = f2bf(v - bf2f(h));
        }
        if (lane16 == 0) b1[o] = beta[o] - mean[o] * sc;
    }
}

// ================= NT MFMA GEMM =================
// C[m,n] = sum_k A[m,k]*B[n,k]; 128x128 tile, 256 thr (2x2 waves of 64x64), BK=32.
// SPLIT=3: 3 passes (hh,hl,lh). EPI: 0=energy partial store, 1=relu+hi/lo bf16, 2=bias+f32.
template <int SPLIT, int EPI>
__global__ __launch_bounds__(256) void gemm_nt(
    const u16* __restrict__ Ah, const u16* __restrict__ Al, long aStride,
    const u16* __restrict__ Bh, const u16* __restrict__ Bl, long bStride,
    int K, int kLen,
    const float* __restrict__ bias,
    float* __restrict__ outF, long oStrideF,
    u16* __restrict__ oHi, u16* __restrict__ oLo, long oStrideH,
    int ldOut) {
    __shared__ u16 AhS[4096];
    __shared__ u16 BhS[4096];
    __shared__ u16 AlS[SPLIT == 3 ? 4096 : 8];
    __shared__ u16 BlS[SPLIT == 3 ? 4096 : 8];

    int m0, n0, kBeg;
    if (EPI == 0) {
        kBeg = blockIdx.x * kLen;
        m0 = (blockIdx.y >> 1) * 128;
        n0 = (blockIdx.y & 1) * 128;
    } else {
        kBeg = 0;
        n0 = blockIdx.x * 128;
        m0 = blockIdx.y * 128;
    }
    int bz = blockIdx.z;
    int tid = threadIdx.x;
    int wave = tid >> 6, lane = tid & 63;

    int c0 = wave * 128 + lane;
    int c1 = c0 + 64;
    int r0 = c0 >> 2, k0 = (c0 & 3) * 8;
    int r1 = c1 >> 2, k1 = (c1 & 3) * 8;
    const u16* gAh0 = Ah + (size_t)bz * aStride + (size_t)(m0 + r0) * K + kBeg + k0;
    const u16* gAh1 = Ah + (size_t)bz * aStride + (size_t)(m0 + r1) * K + kBeg + k1;
    const u16* gBh0 = Bh + (size_t)bz * bStride + (size_t)(n0 + r0) * K + kBeg + k0;
    const u16* gBh1 = Bh + (size_t)bz * bStride + (size_t)(n0 + r1) * K + kBeg + k1;
    const u16 *gAl0 = nullptr, *gAl1 = nullptr, *gBl0 = nullptr, *gBl1 = nullptr;
    if (SPLIT == 3) {
        gAl0 = Al + (size_t)bz * aStride + (size_t)(m0 + r0) * K + kBeg + k0;
        gAl1 = Al + (size_t)bz * aStride + (size_t)(m0 + r1) * K + kBeg + k1;
        gBl0 = Bl + (size_t)bz * bStride + (size_t)(n0 + r0) * K + kBeg + k0;
        gBl1 = Bl + (size_t)bz * bStride + (size_t)(n0 + r1) * K + kBeg + k1;
    }

    int quad = lane >> 4, l15 = lane & 15;
    int wm = wave >> 1, wn = wave & 1;
    int aBase = (wm * 64 + l15) * 32 + quad * 8;
    int bBase = (wn * 64 + l15) * 32 + quad * 8;

    f32x4 zero = {0.f, 0.f, 0.f, 0.f};
    f32x4 acc[4][4];
#pragma unroll
    for (int i = 0; i < 4; ++i)
#pragma unroll
        for (int j = 0; j < 4; ++j) acc[i][j] = zero;

    for (int kb = 0; kb < kLen; kb += 32) {
        __syncthreads();
        gld16(gAh0, AhS + c0 * 8);
        gld16(gAh1, AhS + c1 * 8);
        gld16(gBh0, BhS + c0 * 8);
        gld16(gBh1, BhS + c1 * 8);
        gAh0 += 32; gAh1 += 32; gBh0 += 32; gBh1 += 32;
        if (SPLIT == 3) {
            gld16(gAl0, AlS + c0 * 8);
            gld16(gAl1, AlS + c1 * 8);
            gld16(gBl0, BlS + c0 * 8);
            gld16(gBl1, BlS + c1 * 8);
            gAl0 += 32; gAl1 += 32; gBl0 += 32; gBl1 += 32;
        }
        __syncthreads();

        bf16x8 a_h[4], b_h[4], a_l[4], b_l[4];
#pragma unroll
        for (int t = 0; t < 4; ++t) {
            a_h[t] = *(const bf16x8*)&AhS[aBase + t * 512];
            b_h[t] = *(const bf16x8*)&BhS[bBase + t * 512];
            if (SPLIT == 3) {
                a_l[t] = *(const bf16x8*)&AlS[aBase + t * 512];
                b_l[t] = *(const bf16x8*)&BlS[bBase + t * 512];
            }
        }
#pragma unroll
        for (int mt = 0; mt < 4; ++mt)
#pragma unroll
            for (int nt = 0; nt < 4; ++nt) {
                acc[mt][nt] = __builtin_amdgcn_mfma_f32_16x16x32_bf16(a_h[mt], b_h[nt], acc[mt][nt], 0, 0, 0);
                if (SPLIT == 3) {
                    acc[mt][nt] = __builtin_amdgcn_mfma_f32_16x16x32_bf16(a_h[mt], b_l[nt], acc[mt][nt], 0, 0, 0);
                    acc[mt][nt] = __builtin_amdgcn_mfma_f32_16x16x32_bf16(a_l[mt], b_h[nt], acc[mt][nt], 0, 0, 0);
                }
            }
    }

    // epilogue: row = m0+wm*64+mt*16+quad*4+r, col = n0+wn*64+nt*16+l15
    float* Ce = nullptr;
    if (EPI == 0) Ce = outF + ((size_t)(blockIdx.x * gridDim.z + bz)) * 65536;
#pragma unroll
    for (int mt = 0; mt < 4; ++mt) {
#pragma unroll
        for (int r = 0; r < 4; ++r) {
            int row = m0 + wm * 64 + mt * 16 + quad * 4 + r;
            float bi = (EPI != 0) ? bias[row] : 0.f;
#pragma unroll
            for (int nt = 0; nt < 4; ++nt) {
                int cc = n0 + wn * 64 + nt * 16 + l15;
                float v = acc[mt][nt][r];
                if (EPI == 0) {
                    Ce[(size_t)row * ldOut + cc] = v;
                } else if (EPI == 1) {
                    v = fmaxf(v + bi, 0.f);
                    u16 h = f2bf(v);
                    size_t o = (size_t)bz * oStrideH + (size_t)row * ldOut + cc;
                    oHi[o] = h;
                    oLo[o] = f2bf(v - bf2f(h));
                } else {
                    outF[(size_t)bz * oStrideF + (size_t)row * ldOut + cc] = v + bi;
                }
            }
        }
    }
}

// ================= U1: softmax(-sum(Ep)) | transpose qhi -> qT =================
// blocks [0,1024)      : softmax row (n*256+d), reduce 32 split partials
// blocks [1024,5120)   : transpose qhi [4][256][16384] -> qT [4][16384][256]
__global__ __launch_bounds__(256) void post_kernel(const float* __restrict__ Ep,
                                                   float* __restrict__ att,
                                                   const u16* __restrict__ qhi,
                                                   u16* __restrict__ qT) {
    __shared__ u16 T[64][65];
    __shared__ float red[4], red2[4];
    int b = blockIdx.x;
    int t = threadIdx.x;
    if (b < 1024) {
        int n = b >> 8, d = b & 255;
        const float* p = Ep + ((size_t)n * 256 + d) * 256 + t;
        float v = 0.f;
#pragma unroll 8
        for (int s = 0; s < 32; ++s) v += p[(size_t)s * 262144];
        float m = v;
#pragma unroll
        for (int o = 32; o > 0; o >>= 1) m = fminf(m, __shfl_xor(m, o, 64));
        int lane = t & 63, wid = t >> 6;
        if (lane == 0) red[wid] = m;
        __syncthreads();
        m = fminf(fminf(red[0], red[1]), fminf(red[2], red[3]));
        float e = expf(m - v);
        float s = e;
#pragma unroll
        for (int o = 32; o > 0; o >>= 1) s += __shfl_xor(s, o, 64);
        if (lane == 0) red2[wid] = s;
        __syncthreads();
        s = red2[0] + red2[1] + red2[2] + red2[3];
        att[(size_t)b * 256 + t] = e / s;
    } else {
        int i = b - 1024;
        int s0 = (i & 255) * 64;
        int d0 = ((i >> 8) & 3) * 64;
        size_t sb = (size_t)(i >> 10) * 4194304;
#pragma unroll
        for (int p = 0; p < 2; ++p) {
            int idx = t + p * 256;
            int row = idx >> 3, c8 = (idx & 7) * 8;
            u16 v[8];
            *(uint4*)v = *(const uint4*)&qhi[sb + (size_t)(d0 + row) * S_DIM + s0 + c8];
#pragma unroll
            for (int j = 0; j < 8; ++j) T[c8 + j][row] = v[j];
        }
        __syncthreads();
#pragma unroll
        for (int p = 0; p < 2; ++p) {
            int idx = t + p * 256;
            int row = idx >> 3, c8 = (idx & 7) * 8;
            u16 v[8];
#pragma unroll
            for (int j = 0; j < 8; ++j) v[j] = T[row][c8 + j];
            *(uint4*)&qT[sb + (size_t)(s0 + row) * C_DIM + d0 + c8] = *(uint4*)v;
        }
    }
}

// ================= M2h[n,o,d] = bf16( sum_c w2[o,c]*att[n,d,c] ) =================
__global__ __launch_bounds__(256) void m2h_kernel(const float* __restrict__ w2,
                                                  const float* __restrict__ att,
                                                  u16* __restrict__ M2h) {
    int t = blockIdx.x * 256 + threadIdx.x;
    int d = t & 255, o = (t >> 8) & 255, n = t >> 16;
    const float4* wr = (const float4*)(w2 + (size_t)o * C_DIM);
    const float4* ar = (const float4*)(att + ((size_t)n * C_DIM + d) * C_DIM);
    float s = 0.0f;
#pragma unroll 4
    for (int c4 = 0; c4 < 64; ++c4) {
        float4 w = wr[c4];
        float4 a = ar[c4];
        s += w.x * a.x + w.y * a.y + w.z * a.z + w.w * a.w;
    }
    M2h[((size_t)n * C_DIM + o) * C_DIM + d] = f2bf(s);
}

extern "C" void kernel_launch(void* const* d_in, const int* in_sizes, int n_in,
                              void* d_out, int out_size, void* d_ws, size_t ws_size,
                              hipStream_t stream) {
    const float* feat   = (const float*)d_in[0];
    const float* coarse = (const float*)d_in[1];
    const float* w1     = (const float*)d_in[2];
    const float* gamma  = (const float*)d_in[3];
    const float* beta   = (const float*)d_in[4];
    const float* mean   = (const float*)d_in[5];
    const float* var    = (const float*)d_in[6];
    const float* w2     = (const float*)d_in[7];
    const float* b2     = (const float*)d_in[8];
    float* out = (float*)d_out;

    char* base = (char*)d_ws;  // ~338 MB of 512 MB
    u16* qhi   = (u16*)(base);                   // [4][256][16384]
    u16* qlo   = (u16*)(base + 33554432);
    u16* khi   = (u16*)(base + 67108864);        // [4][256][16384]
    u16* klo   = (u16*)(base + 100663296);
    u16* fThi  = (u16*)(base + 134217728);       // [4][16384][512]
    u16* fTlo  = (u16*)(base + 201326592);
    u16* qT    = (u16*)(base + 268435456);       // [4][16384][256]
    float* Ep  = (float*)(base + 301989888);     // [32][4][256][256]
    float* att = (float*)(base + 335544320);     // [4][256][256]
    u16* M2h   = (u16*)(base + 336592896);
    u16* w1hi  = (u16*)(base + 337117184);
    u16* w1lo  = (u16*)(base + 337379328);
    float* b1  = (float*)(base + 337641472);

    // U0: all input movement (transpose+split feat, split q, fold w1)
    prep_kernel<<<12304, 256, 0, stream>>>(feat, coarse, w1, gamma, beta, mean, var,
                                           fThi, fTlo, qhi, qlo, w1hi, w1lo, b1);

    // conv1+BN+relu -> k hi/lo, all batches
    gemm_nt<3, 1><<<dim3(128, 2, 4), 256, 0, stream>>>(
        w1hi, w1lo, 0, fThi, fTlo, 8388608, CIN, CIN, b1,
        nullptr, 0, khi, klo, 4194304, S_DIM);

    // energy partials: 32 splits x 4 tiles x 4 batches
    gemm_nt<3, 0><<<dim3(32, 4, 4), 256, 0, stream>>>(
        qhi, qlo, 4194304, khi, klo, 4194304, S_DIM, 512, nullptr,
        Ep, 65536, nullptr, nullptr, 0, C_DIM);

    // U1: softmax(-E) + transpose q
    post_kernel<<<5120, 256, 0, stream>>>(Ep, att, qhi, qT);

    m2h_kernel<<<1024, 256, 0, stream>>>(w2, att, M2h);

    // out = M2 @ qT + b2
    gemm_nt<1, 2><<<dim3(128, 2, 4), 256, 0, stream>>>(
        M2h, nullptr, 65536, qT, nullptr, 4194304, C_DIM, C_DIM, b2,
        out, 4194304, nullptr, nullptr, 0, S_DIM);
}

// Round 4
// 447.508 us; speedup vs baseline: 2.1407x; 1.1088x over previous
//
#include <hip/hip_runtime.h>

// N=4, Cin=512, C=D=256, S=H*W=16384
// prep   : split coarse -> q hi/lo bf16 | fold BN into w1 -> hi/lo      (movement, 134 MB)
// conv   : k = relu(BN(conv1)) NT-MFMA 3-pass; A=w1 hi/lo (LDS b128),
//          B = feat fp32 staged RAW into LDS (gld_lds w4), column-gather + cvt -> frags.
//          No global transpose of feat!  Output k hi/lo bf16.
// energy : E_part[64 splits] = q.k^T NT-MFMA 3-pass (bf16 hi/lo b128 path), partial stores
// softmax: att = softmax(-sum Ep) over c  (max-shift cancels)
// m2h    : M2[o,d] = w2 @ att^T -> bf16
// final  : out = M2 @ q + b2; A=M2h b128, B = coarse fp32 column-gather (1-pass hi), fp32 out
// Precision: hi/lo bf16 split keeps |dE|~1e-3 (plain bf16 -> ~0.8 -> softmax flips near-ties).
// LDS fp32 tiles use row stride 133: column-gather banks (8q+5j+n)%32 = 2-way = free.

#define S_DIM 16384
#define C_DIM 256
#define CIN 512

typedef unsigned short u16;
typedef __attribute__((ext_vector_type(8))) short bf16x8;
typedef __attribute__((ext_vector_type(4))) float f32x4;

__device__ __forceinline__ u16 f2bf(float x) {
    unsigned u = __float_as_uint(x);
    u += 0x7fff + ((u >> 16) & 1);
    return (u16)(u >> 16);
}
__device__ __forceinline__ float bf2f(u16 h) {
    return __uint_as_float(((unsigned)h) << 16);
}
__device__ __forceinline__ void gld16(const u16* g, u16* l) {
    __builtin_amdgcn_global_load_lds((const __attribute__((address_space(1))) void*)g,
                                     (__attribute__((address_space(3))) void*)l, 16, 0, 0);
}
__device__ __forceinline__ void gld4(const float* g, float* l) {
    __builtin_amdgcn_global_load_lds((const __attribute__((address_space(1))) void*)g,
                                     (__attribute__((address_space(3))) void*)l, 4, 0, 0);
}

// ================= prep: split coarse -> q hi/lo | fold w1 =================
__global__ __launch_bounds__(256) void prep_kernel(
    const float* __restrict__ coarse, const float* __restrict__ w1,
    const float* __restrict__ gamma, const float* __restrict__ beta,
    const float* __restrict__ mean, const float* __restrict__ var,
    u16* __restrict__ qhi, u16* __restrict__ qlo,
    u16* __restrict__ w1hi, u16* __restrict__ w1lo, float* __restrict__ b1) {
    int b = blockIdx.x;
    int t = threadIdx.x;
    if (b < 4096) {
        size_t i = (size_t)b * 256 + t;
        for (size_t c = i; c < 4194304u; c += 1048576u) {
            float4 v = ((const float4*)coarse)[c];
            float vv[4] = {v.x, v.y, v.z, v.w};
            u16 h[4], l[4];
#pragma unroll
            for (int j = 0; j < 4; ++j) {
                h[j] = f2bf(vv[j]);
                l[j] = f2bf(vv[j] - bf2f(h[j]));
            }
            *(uint2*)&qhi[c * 4] = *(uint2*)h;
            *(uint2*)&qlo[c * 4] = *(uint2*)l;
        }
    } else {
        int o = (b - 4096) * 16 + (t >> 4);
        int lane16 = t & 15;
        float sc = gamma[o] * rsqrtf(var[o] + 1e-5f);
        for (int i = lane16; i < CIN; i += 16) {
            float v = w1[o * CIN + i] * sc;
            u16 h = f2bf(v);
            w1hi[o * CIN + i] = h;
            w1lo[o * CIN + i] = f2bf(v - bf2f(h));
        }
        if (lane16 == 0) b1[o] = beta[o] - mean[o] * sc;
    }
}

// ================= conv: k = relu(BN(w1 @ feat)), 3-pass hi/lo =================
// grid (128 s-tiles, 2 m-tiles, 4 batch). B staged as raw fp32, column-gathered.
__global__ __launch_bounds__(256) void conv_kernel(
    const u16* __restrict__ w1hi, const u16* __restrict__ w1lo,
    const float* __restrict__ feat, const float* __restrict__ b1,
    u16* __restrict__ khi, u16* __restrict__ klo) {
    __shared__ u16 AhS[4096], AlS[4096];
    __shared__ float BfS[32 * 133];
    int s0 = blockIdx.x * 128;
    int m0 = blockIdx.y * 128;
    int bz = blockIdx.z;
    int tid = threadIdx.x, wave = tid >> 6, lane = tid & 63;

    int c0 = wave * 128 + lane, c1 = c0 + 64;
    int r0 = c0 >> 2, k0 = (c0 & 3) * 8;
    int r1 = c1 >> 2, k1 = (c1 & 3) * 8;
    const u16* gA0h = w1hi + (size_t)(m0 + r0) * CIN + k0;
    const u16* gA1h = w1hi + (size_t)(m0 + r1) * CIN + k1;
    const u16* gA0l = w1lo + (size_t)(m0 + r0) * CIN + k0;
    const u16* gA1l = w1lo + (size_t)(m0 + r1) * CIN + k1;
    const float* fB = feat + (size_t)bz * ((size_t)CIN * S_DIM) + s0 + lane;

    int quad = lane >> 4, l15 = lane & 15;
    int wm = wave >> 1, wn = wave & 1;
    int aBase = (wm * 64 + l15) * 32 + quad * 8;

    f32x4 zero = {0.f, 0.f, 0.f, 0.f};
    f32x4 acc[4][4];
#pragma unroll
    for (int i = 0; i < 4; ++i)
#pragma unroll
        for (int j = 0; j < 4; ++j) acc[i][j] = zero;

    for (int kb = 0; kb < CIN; kb += 32) {
        __syncthreads();
        gld16(gA0h, AhS + c0 * 8);
        gld16(gA1h, AhS + c1 * 8);
        gld16(gA0l, AlS + c0 * 8);
        gld16(gA1l, AlS + c1 * 8);
        gA0h += 32; gA1h += 32; gA0l += 32; gA1l += 32;
#pragma unroll
        for (int j = 0; j < 16; ++j) {
            int cc = wave * 16 + j;
            int i = cc >> 1, h = cc & 1;
            gld4(fB + (size_t)(kb + i) * S_DIM + h * 64, BfS + i * 133 + h * 64 + lane);
        }
        __syncthreads();

        bf16x8 a_h[4], a_l[4];
#pragma unroll
        for (int t = 0; t < 4; ++t) {
            a_h[t] = *(const bf16x8*)&AhS[aBase + t * 512];
            a_l[t] = *(const bf16x8*)&AlS[aBase + t * 512];
        }
        bf16x8 b_h[4], b_l[4];
#pragma unroll
        for (int nt = 0; nt < 4; ++nt) {
            int n = wn * 64 + nt * 16 + l15;
            union { u16 u[8]; bf16x8 v; } th, tl;
#pragma unroll
            for (int j = 0; j < 8; ++j) {
                float f = BfS[(quad * 8 + j) * 133 + n];
                u16 h = f2bf(f);
                th.u[j] = h;
                tl.u[j] = (u16)(__float_as_uint(f - bf2f(h)) >> 16);
            }
            b_h[nt] = th.v;
            b_l[nt] = tl.v;
        }
#pragma unroll
        for (int mt = 0; mt < 4; ++mt)
#pragma unroll
            for (int nt = 0; nt < 4; ++nt) {
                acc[mt][nt] = __builtin_amdgcn_mfma_f32_16x16x32_bf16(a_h[mt], b_h[nt], acc[mt][nt], 0, 0, 0);
                acc[mt][nt] = __builtin_amdgcn_mfma_f32_16x16x32_bf16(a_h[mt], b_l[nt], acc[mt][nt], 0, 0, 0);
                acc[mt][nt] = __builtin_amdgcn_mfma_f32_16x16x32_bf16(a_l[mt], b_h[nt], acc[mt][nt], 0, 0, 0);
            }
    }

#pragma unroll
    for (int mt = 0; mt < 4; ++mt) {
#pragma unroll
        for (int r = 0; r < 4; ++r) {
            int row = m0 + wm * 64 + mt * 16 + quad * 4 + r;
            float bi = b1[row];
#pragma unroll
            for (int nt = 0; nt < 4; ++nt) {
                int cc = s0 + wn * 64 + nt * 16 + l15;
                float v = fmaxf(acc[mt][nt][r] + bi, 0.f);
                u16 h = f2bf(v);
                size_t o = (size_t)bz * 4194304 + (size_t)row * S_DIM + cc;
                khi[o] = h;
                klo[o] = f2bf(v - bf2f(h));
            }
        }
    }
}

// ================= energy: Ep[split] = q.k^T (3-pass hi/lo), 64 splits =================
__global__ __launch_bounds__(256) void energy_kernel(
    const u16* __restrict__ qhi, const u16* __restrict__ qlo,
    const u16* __restrict__ khi, const u16* __restrict__ klo,
    float* __restrict__ Ep) {
    __shared__ u16 AhS[4096], BhS[4096], AlS[4096], BlS[4096];
    int kBeg = blockIdx.x * 256;
    int m0 = (blockIdx.y >> 1) * 128;
    int n0 = (blockIdx.y & 1) * 128;
    int bz = blockIdx.z;
    int tid = threadIdx.x, wave = tid >> 6, lane = tid & 63;

    int c0 = wave * 128 + lane, c1 = c0 + 64;
    int r0 = c0 >> 2, k0 = (c0 & 3) * 8;
    int r1 = c1 >> 2, k1 = (c1 & 3) * 8;
    size_t bo = (size_t)bz * 4194304;
    const u16* gA0h = qhi + bo + (size_t)(m0 + r0) * S_DIM + kBeg + k0;
    const u16* gA1h = qhi + bo + (size_t)(m0 + r1) * S_DIM + kBeg + k1;
    const u16* gB0h = khi + bo + (size_t)(n0 + r0) * S_DIM + kBeg + k0;
    const u16* gB1h = khi + bo + (size_t)(n0 + r1) * S_DIM + kBeg + k1;
    const u16* gA0l = qlo + bo + (size_t)(m0 + r0) * S_DIM + kBeg + k0;
    const u16* gA1l = qlo + bo + (size_t)(m0 + r1) * S_DIM + kBeg + k1;
    const u16* gB0l = klo + bo + (size_t)(n0 + r0) * S_DIM + kBeg + k0;
    const u16* gB1l = klo + bo + (size_t)(n0 + r1) * S_DIM + kBeg + k1;

    int quad = lane >> 4, l15 = lane & 15;
    int wm = wave >> 1, wn = wave & 1;
    int aBase = (wm * 64 + l15) * 32 + quad * 8;
    int bBase = (wn * 64 + l15) * 32 + quad * 8;

    f32x4 zero = {0.f, 0.f, 0.f, 0.f};
    f32x4 acc[4][4];
#pragma unroll
    for (int i = 0; i < 4; ++i)
#pragma unroll
        for (int j = 0; j < 4; ++j) acc[i][j] = zero;

    for (int kb = 0; kb < 256; kb += 32) {
        __syncthreads();
        gld16(gA0h, AhS + c0 * 8);
        gld16(gA1h, AhS + c1 * 8);
        gld16(gB0h, BhS + c0 * 8);
        gld16(gB1h, BhS + c1 * 8);
        gld16(gA0l, AlS + c0 * 8);
        gld16(gA1l, AlS + c1 * 8);
        gld16(gB0l, BlS + c0 * 8);
        gld16(gB1l, BlS + c1 * 8);
        gA0h += 32; gA1h += 32; gB0h += 32; gB1h += 32;
        gA0l += 32; gA1l += 32; gB0l += 32; gB1l += 32;
        __syncthreads();

        bf16x8 a_h[4], b_h[4], a_l[4], b_l[4];
#pragma unroll
        for (int t = 0; t < 4; ++t) {
            a_h[t] = *(const bf16x8*)&AhS[aBase + t * 512];
            b_h[t] = *(const bf16x8*)&BhS[bBase + t * 512];
            a_l[t] = *(const bf16x8*)&AlS[aBase + t * 512];
            b_l[t] = *(const bf16x8*)&BlS[bBase + t * 512];
        }
#pragma unroll
        for (int mt = 0; mt < 4; ++mt)
#pragma unroll
            for (int nt = 0; nt < 4; ++nt) {
                acc[mt][nt] = __builtin_amdgcn_mfma_f32_16x16x32_bf16(a_h[mt], b_h[nt], acc[mt][nt], 0, 0, 0);
                acc[mt][nt] = __builtin_amdgcn_mfma_f32_16x16x32_bf16(a_h[mt], b_l[nt], acc[mt][nt], 0, 0, 0);
                acc[mt][nt] = __builtin_amdgcn_mfma_f32_16x16x32_bf16(a_l[mt], b_h[nt], acc[mt][nt], 0, 0, 0);
            }
    }

    float* Ce = Ep + ((size_t)(blockIdx.x * 4 + bz)) * 65536;
#pragma unroll
    for (int mt = 0; mt < 4; ++mt)
#pragma unroll
        for (int r = 0; r < 4; ++r) {
            int row = m0 + wm * 64 + mt * 16 + quad * 4 + r;
#pragma unroll
            for (int nt = 0; nt < 4; ++nt) {
                int cc = n0 + wn * 64 + nt * 16 + l15;
                Ce[(size_t)row * C_DIM + cc] = acc[mt][nt][r];
            }
        }
}

// ================= softmax(-sum Ep) over c =================
__global__ __launch_bounds__(256) void softmax_kernel(const float* __restrict__ Ep,
                                                      float* __restrict__ att) {
    __shared__ float red[4], red2[4];
    int b = blockIdx.x;  // n*256+d
    int t = threadIdx.x;
    const float* p = Ep + (size_t)b * 256 + t;
    float v = 0.f;
#pragma unroll 8
    for (int s = 0; s < 64; ++s) v += p[(size_t)s * 262144];
    float m = v;
#pragma unroll
    for (int o = 32; o > 0; o >>= 1) m = fminf(m, __shfl_xor(m, o, 64));
    int lane = t & 63, wid = t >> 6;
    if (lane == 0) red[wid] = m;
    __syncthreads();
    m = fminf(fminf(red[0], red[1]), fminf(red[2], red[3]));
    float e = expf(m - v);
    float s = e;
#pragma unroll
    for (int o = 32; o > 0; o >>= 1) s += __shfl_xor(s, o, 64);
    if (lane == 0) red2[wid] = s;
    __syncthreads();
    s = red2[0] + red2[1] + red2[2] + red2[3];
    att[(size_t)b * 256 + t] = e / s;
}

// ================= M2h[n,o,d] = bf16( sum_c w2[o,c]*att[n,d,c] ) =================
__global__ __launch_bounds__(256) void m2h_kernel(const float* __restrict__ w2,
                                                  const float* __restrict__ att,
                                                  u16* __restrict__ M2h) {
    int t = blockIdx.x * 256 + threadIdx.x;
    int d = t & 255, o = (t >> 8) & 255, n = t >> 16;
    const float4* wr = (const float4*)(w2 + (size_t)o * C_DIM);
    const float4* ar = (const float4*)(att + ((size_t)n * C_DIM + d) * C_DIM);
    float s = 0.0f;
#pragma unroll 4
    for (int c4 = 0; c4 < 64; ++c4) {
        float4 w = wr[c4];
        float4 a = ar[c4];
        s += w.x * a.x + w.y * a.y + w.z * a.z + w.w * a.w;
    }
    M2h[((size_t)n * C_DIM + o) * C_DIM + d] = f2bf(s);
}

// ================= final: out = M2 @ q + b2 (1-pass) =================
// A = M2h [256 o][256 d] bf16; B = coarse fp32 [d][s], staged raw + column-gather.
__global__ __launch_bounds__(256) void final_kernel(
    const u16* __restrict__ M2h, const float* __restrict__ coarse,
    const float* __restrict__ b2, float* __restrict__ out) {
    __shared__ u16 AhS[4096];
    __shared__ float BfS[32 * 133];
    int s0 = blockIdx.x * 128;
    int m0 = blockIdx.y * 128;
    int bz = blockIdx.z;
    int tid = threadIdx.x, wave = tid >> 6, lane = tid & 63;

    int c0 = wave * 128 + lane, c1 = c0 + 64;
    int r0 = c0 >> 2, k0 = (c0 & 3) * 8;
    int r1 = c1 >> 2, k1 = (c1 & 3) * 8;
    const u16* gA0 = M2h + (size_t)bz * 65536 + (size_t)(m0 + r0) * C_DIM + k0;
    const u16* gA1 = M2h + (size_t)bz * 65536 + (size_t)(m0 + r1) * C_DIM + k1;
    const float* fB = coarse + (size_t)bz * 4194304 + s0 + lane;

    int quad = lane >> 4, l15 = lane & 15;
    int wm = wave >> 1, wn = wave & 1;
    int aBase = (wm * 64 + l15) * 32 + quad * 8;

    f32x4 zero = {0.f, 0.f, 0.f, 0.f};
    f32x4 acc[4][4];
#pragma unroll
    for (int i = 0; i < 4; ++i)
#pragma unroll
        for (int j = 0; j < 4; ++j) acc[i][j] = zero;

    for (int kb = 0; kb < C_DIM; kb += 32) {
        __syncthreads();
        gld16(gA0, AhS + c0 * 8);
        gld16(gA1, AhS + c1 * 8);
        gA0 += 32; gA1 += 32;
#pragma unroll
        for (int j = 0; j < 16; ++j) {
            int cc = wave * 16 + j;
            int i = cc >> 1, h = cc & 1;
            gld4(fB + (size_t)(kb + i) * S_DIM + h * 64, BfS + i * 133 + h * 64 + lane);
        }
        __syncthreads();

        bf16x8 a_h[4];
#pragma unroll
        for (int t = 0; t < 4; ++t) a_h[t] = *(const bf16x8*)&AhS[aBase + t * 512];
        bf16x8 b_h[4];
#pragma unroll
        for (int nt = 0; nt < 4; ++nt) {
            int n = wn * 64 + nt * 16 + l15;
            union { u16 u[8]; bf16x8 v; } th;
#pragma unroll
            for (int j = 0; j < 8; ++j) th.u[j] = f2bf(BfS[(quad * 8 + j) * 133 + n]);
            b_h[nt] = th.v;
        }
#pragma unroll
        for (int mt = 0; mt < 4; ++mt)
#pragma unroll
            for (int nt = 0; nt < 4; ++nt)
                acc[mt][nt] = __builtin_amdgcn_mfma_f32_16x16x32_bf16(a_h[mt], b_h[nt], acc[mt][nt], 0, 0, 0);
    }

#pragma unroll
    for (int mt = 0; mt < 4; ++mt)
#pragma unroll
        for (int r = 0; r < 4; ++r) {
            int row = m0 + wm * 64 + mt * 16 + quad * 4 + r;
            float bi = b2[row];
#pragma unroll
            for (int nt = 0; nt < 4; ++nt) {
                int cc = s0 + wn * 64 + nt * 16 + l15;
                out[(size_t)bz * 4194304 + (size_t)row * S_DIM + cc] = acc[mt][nt][r] + bi;
            }
        }
}

extern "C" void kernel_launch(void* const* d_in, const int* in_sizes, int n_in,
                              void* d_out, int out_size, void* d_ws, size_t ws_size,
                              hipStream_t stream) {
    const float* feat   = (const float*)d_in[0];
    const float* coarse = (const float*)d_in[1];
    const float* w1     = (const float*)d_in[2];
    const float* gamma  = (const float*)d_in[3];
    const float* beta   = (const float*)d_in[4];
    const float* mean   = (const float*)d_in[5];
    const float* var    = (const float*)d_in[6];
    const float* w2     = (const float*)d_in[7];
    const float* b2     = (const float*)d_in[8];
    float* out = (float*)d_out;

    char* base = (char*)d_ws;  // ~204 MB
    u16* qhi   = (u16*)(base);                   // [4][256][16384]
    u16* qlo   = (u16*)(base + 33554432);
    u16* khi   = (u16*)(base + 67108864);        // [4][256][16384]
    u16* klo   = (u16*)(base + 100663296);
    float* Ep  = (float*)(base + 134217728);     // [64][4][256][256] = 67 MB
    float* att = (float*)(base + 201326592);     // [4][256][256]
    u16* M2h   = (u16*)(base + 202375168);
    u16* w1hi  = (u16*)(base + 202899456);
    u16* w1lo  = (u16*)(base + 203161600);
    float* b1  = (float*)(base + 203423744);

    prep_kernel<<<4112, 256, 0, stream>>>(coarse, w1, gamma, beta, mean, var,
                                          qhi, qlo, w1hi, w1lo, b1);

    conv_kernel<<<dim3(128, 2, 4), 256, 0, stream>>>(w1hi, w1lo, feat, b1, khi, klo);

    energy_kernel<<<dim3(64, 4, 4), 256, 0, stream>>>(qhi, qlo, khi, klo, Ep);

    softmax_kernel<<<1024, 256, 0, stream>>>(Ep, att);

    m2h_kernel<<<1024, 256, 0, stream>>>(w2, att, M2h);

    final_kernel<<<dim3(128, 2, 4), 256, 0, stream>>>(M2h, coarse, b2, out);
}